// Round 1
// baseline (8063.487 us; speedup 1.0000x reference)
//
#include <hip/hip_runtime.h>
#include <hip/hip_cooperative_groups.h>

namespace cg = cooperative_groups;

#define GN 512
#define GNN (GN * GN)
#define OUT_STEPS 255

// constants from the reference
__device__ __forceinline__ float lin_step() { return 10.0f / 511.0f; }

__global__ __launch_bounds__(256, 4)
void wave_coop(const float* __restrict__ u0,
               const float* __restrict__ alpha,
               float* __restrict__ out)
{
    const int tid  = blockIdx.x * 256 + threadIdx.x;   // 0..65535
    const int base = tid << 2;                         // first of my 4 cells
    const int i    = base >> 9;                        // row (uniform across my 4 cells)
    const int j0   = base & 511;                       // col of first cell

    const float DT2    = 5e-05f * 5e-05f;
    const float DX     = 10.0f / 511.0f;
    const float DX2    = DX * DX;
    const float invDX2 = 1.0f / DX2;

    // ---- wave-speed map c^2 for my 4 cells (computed once, kept in regs) ----
    float amps[4], cxs[4], cys[4];
#pragma unroll
    for (int g = 0; g < 4; ++g) {
        amps[g] = alpha[g];
        cxs[g]  = alpha[4 + g];
        cys[g]  = alpha[8 + g];
    }
    const float xi = -5.0f + (float)i * lin_step();
    float c2[4];
#pragma unroll
    for (int m = 0; m < 4; ++m) {
        const float yj = -5.0f + (float)(j0 + m) * lin_step();
        float c = 2.0f;
#pragma unroll
        for (int g = 0; g < 4; ++g) {
            const float dx = xi - cxs[g];
            const float dy = yj - cys[g];
            c += amps[g] * expf(-(dx * dx + dy * dy));
        }
        c2[m] = c * c;
    }

    const bool row_interior = (i > 0) && (i < GN - 1);
    const bool j_first      = (j0 == 0);        // cell 0 on left boundary
    const bool j_last       = (j0 + 3 == GN - 1); // cell 3 on right boundary

    // current u and previous u at my 4 cells (start: both = u0)
    float4 uc = *reinterpret_cast<const float4*>(u0 + base);
    float4 up = uc;

    cg::grid_group grid = cg::this_grid();

    const float* cur = u0;   // field u_k lives here (u0 first, then out slices)
    for (int s = 0; s < OUT_STEPS; ++s) {
        float4 nw;
        if (!row_interior) {
            nw = make_float4(0.f, 0.f, 0.f, 0.f);
        } else {
            const float4 a = *reinterpret_cast<const float4*>(cur + base - GN);
            const float4 b = *reinterpret_cast<const float4*>(cur + base + GN);
            const float lf = j_first ? 0.0f : cur[base - 1];
            const float rt = j_last  ? 0.0f : cur[base + 4];

            const float n0 = 2.0f * uc.x - up.x +
                DT2 * c2[0] * ((a.x + b.x + lf   + uc.y - 4.0f * uc.x) * invDX2);
            const float n1 = 2.0f * uc.y - up.y +
                DT2 * c2[1] * ((a.y + b.y + uc.x + uc.z - 4.0f * uc.y) * invDX2);
            const float n2 = 2.0f * uc.z - up.z +
                DT2 * c2[2] * ((a.z + b.z + uc.y + uc.w - 4.0f * uc.z) * invDX2);
            const float n3 = 2.0f * uc.w - up.w +
                DT2 * c2[3] * ((a.w + b.w + uc.z + rt   - 4.0f * uc.w) * invDX2);

            nw.x = j_first ? 0.0f : n0;
            nw.y = n1;
            nw.z = n2;
            nw.w = j_last ? 0.0f : n3;
        }

        float* outs = out + (size_t)s * GNN;
        *reinterpret_cast<float4*>(outs + base) = nw;

        up  = uc;
        uc  = nw;
        cur = outs;

        grid.sync();   // release slice s grid-wide before anyone reads it
    }
}

extern "C" void kernel_launch(void* const* d_in, const int* in_sizes, int n_in,
                              void* d_out, int out_size, void* d_ws, size_t ws_size,
                              hipStream_t stream)
{
    const float* u0    = (const float*)d_in[0];
    const float* alpha = (const float*)d_in[1];
    float*       out   = (float*)d_out;

    void* args[] = { (void*)&u0, (void*)&alpha, (void*)&out };
    hipLaunchCooperativeKernel((const void*)wave_coop,
                               dim3(256), dim3(256), args, 0, stream);
}

// Round 2
// 593.278 us; speedup vs baseline: 13.5914x; 13.5914x over previous
//
#include <hip/hip_runtime.h>

#define GN      512
#define TILE    32
#define HALO    15
#define TSTEPS  15          // steps per chunk; 17 chunks * 15 = 255
#define NCHUNK  17
#define REGW    62          // TILE + 2*HALO
#define LSTR    64          // LDS row stride (floats)
#define NTHR    1024

// One chunk: advance 15 time steps for one 32x32 tile, entirely in LDS.
// Trapezoidal (shrinking-region) temporal blocking: step s computes the
// region at halo radius 15-s; cells outside that radius may hold garbage
// but are provably never read by later steps.
__global__ __launch_bounds__(NTHR)
void wave_chunk(const float* __restrict__ ucur,   // u at chunk base
                const float* __restrict__ uprev,  // u at chunk base - 1
                const float* __restrict__ alpha,
                float* __restrict__ out,
                int slice0)                       // first out slice this chunk writes
{
    __shared__ __align__(16) float buf0[(REGW + 1) * LSTR];
    __shared__ __align__(16) float buf1[(REGW + 1) * LSTR];
    __shared__ __align__(16) float c2s [(REGW + 1) * LSTR];

    const int tid = threadIdx.x;
    const int bx  = blockIdx.x & 15;            // 16x16 tiles
    const int by  = blockIdx.x >> 4;
    const int ti0 = by * TILE, tj0 = bx * TILE;
    const int gi0 = ti0 - HALO, gj0 = tj0 - HALO; // region origin (may be <0)

    const float DX = 10.0f / 511.0f;
    const float K  = (5e-5f * 5e-5f) / (DX * DX); // DT2/DX2

    float amp[4], cx[4], cy[4];
#pragma unroll
    for (int g = 0; g < 4; ++g) {
        amp[g] = alpha[g];
        cx[g]  = alpha[4 + g];
        cy[g]  = alpha[8 + g];
    }

    // ---- load region (2 time levels) + compute c^2 map ----
    {
        const int b = tid & 63;
        for (int a = tid >> 6; a < REGW; a += NTHR / 64) {
            if (b < REGW) {
                const int gi = gi0 + a, gj = gj0 + b;
                const bool in = ((unsigned)gi < GN) && ((unsigned)gj < GN);
                const int gidx = gi * GN + gj;
                buf0[a * LSTR + b] = in ? ucur[gidx]  : 0.0f;
                buf1[a * LSTR + b] = in ? uprev[gidx] : 0.0f;
                const float X = -5.0f + (float)gi * DX;
                const float Y = -5.0f + (float)gj * DX;
                float c = 2.0f;
#pragma unroll
                for (int g = 0; g < 4; ++g) {
                    const float dx = X - cx[g], dy = Y - cy[g];
                    c += amp[g] * __expf(-(dx * dx + dy * dy));
                }
                c2s[a * LSTR + b] = c * c;
            }
        }
    }
    __syncthreads();

    float* A  = buf0;   // current time level
    float* Bp = buf1;   // previous time level; overwritten per-cell with new

    const int tx   = tid & 15;   // group column (4 cells each)
    const int ty   = tid >> 4;   // region row 0..63
    const int wrow = tid >> 5;   // write-pass: 32x32 tile, 1 cell/thread
    const int wcol = tid & 31;

    for (int s = 1; s <= TSTEPS; ++s) {
        const int o = s;                 // region offset this step
        const int W = REGW - 2 * s;      // region width: 60, 58, ..., 32
        const int gbase = o & ~3;        // 16B-aligned group base
        const int gend  = o + W;
        const int ac = gbase + 4 * tx;   // absolute col of my 4-cell group
        if (ty < W && ac < gend) {
            const int a   = o + ty;      // absolute row
            const int idx = a * LSTR + ac;
            const float4 up = *(const float4*)(A + idx - LSTR);
            const float4 dn = *(const float4*)(A + idx + LSTR);
            const float4 ct = *(const float4*)(A + idx);
            const float  lf = A[idx - 1];
            const float  rt = A[idx + 4];
            const float4 pv = *(const float4*)(Bp + idx);
            const float4 cc = *(const float4*)(c2s + idx);
            const int gi  = gi0 + a;
            const int gjb = gj0 + ac;
            const bool rin = (gi >= 1) & (gi <= GN - 2);
            float4 nw;
            nw.x = (rin & (gjb + 0 >= 1) & (gjb + 0 <= GN - 2))
                 ? 2.0f * ct.x - pv.x + K * cc.x * (up.x + dn.x + lf   + ct.y - 4.0f * ct.x) : 0.0f;
            nw.y = (rin & (gjb + 1 >= 1) & (gjb + 1 <= GN - 2))
                 ? 2.0f * ct.y - pv.y + K * cc.y * (up.y + dn.y + ct.x + ct.z - 4.0f * ct.y) : 0.0f;
            nw.z = (rin & (gjb + 2 >= 1) & (gjb + 2 <= GN - 2))
                 ? 2.0f * ct.z - pv.z + K * cc.z * (up.z + dn.z + ct.y + ct.w - 4.0f * ct.z) : 0.0f;
            nw.w = (rin & (gjb + 3 >= 1) & (gjb + 3 <= GN - 2))
                 ? 2.0f * ct.w - pv.w + K * cc.w * (up.w + dn.w + ct.z + rt   - 4.0f * ct.w) : 0.0f;
            *(float4*)(Bp + idx) = nw;   // per-cell read-then-write, same thread: safe
        }
        __syncthreads();
        { float* t = A; A = Bp; Bp = t; }   // A now holds the new time level

        // write my tile of this slice (every out cell written; boundary = 0 via mask)
        const float v = A[(HALO + wrow) * LSTR + (HALO + wcol)];
        out[(size_t)(slice0 + s - 1) * (GN * GN)
            + (size_t)(ti0 + wrow) * GN + (tj0 + wcol)] = v;
        // no extra sync needed: next step reads A (just-synced) and writes the
        // other buffer; the write-pass also reads only A.
    }
}

extern "C" void kernel_launch(void* const* d_in, const int* in_sizes, int n_in,
                              void* d_out, int out_size, void* d_ws, size_t ws_size,
                              hipStream_t stream)
{
    const float* u0    = (const float*)d_in[0];
    const float* alpha = (const float*)d_in[1];
    float*       out   = (float*)d_out;
    const size_t GNN   = (size_t)GN * GN;

    for (int k = 0; k < NCHUNK; ++k) {
        // chunk k advances u_{15k} -> u_{15k+15}, writing out slices [15k, 15k+15)
        // out slice s holds u_{s+1}; u_{15k} = out slice 15k-1 (u0 for k=0)
        const float* uc = (k == 0) ? u0 : out + (size_t)(TSTEPS * k - 1) * GNN;
        const float* up = (k == 0) ? u0 : out + (size_t)(TSTEPS * k - 2) * GNN;
        wave_chunk<<<dim3(256), dim3(NTHR), 0, stream>>>(uc, up, alpha, out, TSTEPS * k);
    }
}

// Round 3
// 396.931 us; speedup vs baseline: 20.3146x; 1.4947x over previous
//
#include <hip/hip_runtime.h>

#define GN      512
#define GNN     (GN * GN)
#define TILE    32
#define HALO    16          // halo radius = max steps per chunk
#define REGW    64          // TILE + 2*HALO
#define LSTR    68          // LDS row stride in floats (68*4=272 B, 16B-aligned, non-pow2)
#define LROWS   66          // 1 pad row + 64 region rows + 1 pad row
#define NTHR    1024

// Temporal-blocked chunk with register-resident cells.
// Each thread owns 4 consecutive cells (one float4) of the 64x64 region:
// u_cur, u_prev, c^2, boundary mask all in registers. LDS holds only the
// neighbor-exchange surface (double-buffered). Trapezoid invariant: after s
// steps, cells within distance >= s of the region edge are exact; the 32x32
// output tile is at distance >= 16, and nsteps <= 16.
__global__ __launch_bounds__(NTHR)
void wave_chunk(const float* __restrict__ ucur,   // u at chunk base
                const float* __restrict__ uprev,  // u at chunk base - 1
                const float* __restrict__ alpha,
                float* __restrict__ out,
                int slice0, int nsteps)
{
    __shared__ __align__(16) float bufA[LROWS * LSTR];
    __shared__ __align__(16) float bufB[LROWS * LSTR];

    const int tid = threadIdx.x;
    const int r   = tid >> 4;        // region row 0..63
    const int c   = tid & 15;        // 4-cell group 0..15
    const int jc  = c << 2;          // region col of first owned cell

    const int bx  = blockIdx.x & 15;
    const int by  = blockIdx.x >> 4;
    const int ti0 = by * TILE, tj0 = bx * TILE;
    const int gi  = ti0 - HALO + r;      // global row of my cells
    const int gj0 = tj0 - HALO + jc;     // global col of first cell (mult of 4)

    // zero whole LDS (pad rows/cols must read as finite zeros)
    for (int k = tid; k < LROWS * LSTR; k += NTHR) { bufA[k] = 0.0f; bufB[k] = 0.0f; }

    const float DX = 10.0f / 511.0f;
    const float K  = (5e-5f * 5e-5f) / (DX * DX);   // DT2/DX2

    // ---- c^2 for my 4 cells (registers) ----
    float amp[4], cxs[4], cys[4];
#pragma unroll
    for (int g = 0; g < 4; ++g) {
        amp[g] = alpha[g];
        cxs[g] = alpha[4 + g];
        cys[g] = alpha[8 + g];
    }
    const float X = -5.0f + (float)gi * DX;
    float4 c2v;
    {
        float cm[4];
#pragma unroll
        for (int m = 0; m < 4; ++m) {
            const float Y = -5.0f + (float)(gj0 + m) * DX;
            float cv = 2.0f;
#pragma unroll
            for (int g = 0; g < 4; ++g) {
                const float dx = X - cxs[g], dy = Y - cys[g];
                cv += amp[g] * __expf(-(dx * dx + dy * dy));
            }
            cm[m] = cv * cv;
        }
        c2v = make_float4(cm[0], cm[1], cm[2], cm[3]);
    }

    // ---- interior mask (registers); boundary & out-of-domain cells pinned to 0 ----
    const bool rin = (gi >= 1) && (gi <= GN - 2);
    float4 bm;
    bm.x = (rin && gj0 + 0 >= 1 && gj0 + 0 <= GN - 2) ? 1.0f : 0.0f;
    bm.y = (rin && gj0 + 1 >= 1 && gj0 + 1 <= GN - 2) ? 1.0f : 0.0f;
    bm.z = (rin && gj0 + 2 >= 1 && gj0 + 2 <= GN - 2) ? 1.0f : 0.0f;
    bm.w = (rin && gj0 + 3 >= 1 && gj0 + 3 <= GN - 2) ? 1.0f : 0.0f;

    // ---- load my cells (domain width 512 and gj0 % 4 == 0 -> group fully in or out)
    float4 cur4 = make_float4(0.f, 0.f, 0.f, 0.f);
    float4 prv4 = cur4;
    const bool rowin = ((unsigned)gi < GN);
    const bool colin = ((unsigned)gj0 <= (GN - 4));
    if (rowin && colin) {
        const size_t g = (size_t)gi * GN + gj0;
        cur4 = *reinterpret_cast<const float4*>(ucur + g);
        prv4 = *reinterpret_cast<const float4*>(uprev + g);
    }

    const int idx = (r + 1) * LSTR + jc;     // my slot in the exchange surface
    *reinterpret_cast<float4*>(bufA + idx) = cur4;
    __syncthreads();

    const bool inTile = (r >= HALO) && (r < HALO + TILE) &&
                        (jc >= HALO) && (jc < HALO + TILE);

    float* A = bufA;
    float* B = bufB;
    for (int s = 0; s < nsteps; ++s) {
        const float4 up = *reinterpret_cast<const float4*>(A + idx - LSTR);
        const float4 dn = *reinterpret_cast<const float4*>(A + idx + LSTR);
        const float  lf = A[idx - 1];
        const float  rt = A[idx + 4];

        float4 nw;
        nw.x = bm.x * (2.0f * cur4.x - prv4.x + K * c2v.x * (up.x + dn.x + lf     + cur4.y - 4.0f * cur4.x));
        nw.y = bm.y * (2.0f * cur4.y - prv4.y + K * c2v.y * (up.y + dn.y + cur4.x + cur4.z - 4.0f * cur4.y));
        nw.z = bm.z * (2.0f * cur4.z - prv4.z + K * c2v.z * (up.z + dn.z + cur4.y + cur4.w - 4.0f * cur4.z));
        nw.w = bm.w * (2.0f * cur4.w - prv4.w + K * c2v.w * (up.w + dn.w + cur4.z + rt     - 4.0f * cur4.w));

        *reinterpret_cast<float4*>(B + idx) = nw;
        prv4 = cur4;
        cur4 = nw;

        if (inTile) {   // my 4 cells are part of the exact 32x32 tile: store from regs
            *reinterpret_cast<float4*>(out + (size_t)(slice0 + s) * GNN
                                           + (size_t)gi * GN + gj0) = nw;
        }

        __syncthreads();
        float* t = A; A = B; B = t;
    }
}

extern "C" void kernel_launch(void* const* d_in, const int* in_sizes, int n_in,
                              void* d_out, int out_size, void* d_ws, size_t ws_size,
                              hipStream_t stream)
{
    const float* u0    = (const float*)d_in[0];
    const float* alpha = (const float*)d_in[1];
    float*       out   = (float*)d_out;

    // 15 chunks x 16 steps + 1 chunk x 15 steps = 255
    int base = 0;
    for (int k = 0; k < 16; ++k) {
        const int steps = (k < 15) ? 16 : 15;
        const float* uc = (k == 0) ? u0 : out + (size_t)(base - 1) * GNN;
        const float* up = (k == 0) ? u0 : out + (size_t)(base - 2) * GNN;
        wave_chunk<<<dim3(256), dim3(NTHR), 0, stream>>>(uc, up, alpha, out, base, steps);
        base += steps;
    }
}